// Round 8
// baseline (34766.434 us; speedup 1.0000x reference)
//
#include <hip/hip_runtime.h>

typedef __attribute__((ext_vector_type(4))) float floatx4;

#define T_STEPS 512
// d_out is FP32: outputs[512][64][1024], ht[64][1024], ct[64][1024]
#define OUT_HT_OFF 33554432ull
#define OUT_CT_OFF 33619968ull

// ws: c_ws fp32 [64*1024] (256 KiB)
#define WS_NEED (256ull << 10)

// tripwire: ws too small -> distinguishable sentinel (fp32 2.0 in out[0..63])
__global__ void ws_sentinel(float* out) { out[threadIdx.x] = 2.0f; }

// One timestep, pure fp32 VALU. grid 256 WGs x 256 thr.
// WG (rg 0..7, ugg 0..31): batch rows rg*8..+8, units ugg*32..+32 (all 4 gates).
// Thread: s = tid&127 -> (gate = s>>5, u = s&31), rh = tid>>7 -> rows rh*4..+4.
// Each thread: 4 fp32 dot products (4 rows x 1 z-col) over K=2048 = [x_t | h].
// W,R read directly from d_in (row-major, lane-coalesced over cols).
// h feedback read from out[t-1] (exact fp32 h); c state fp32 in ws.
__global__ void __launch_bounds__(256) lstm_step(
    const float* __restrict__ W,      // [1024][4096] fp32
    const float* __restrict__ R,      // [1024][4096] fp32
    const float* __restrict__ bias,   // [4096] fp32
    const float* __restrict__ x,      // [512][64][1024] fp32
    float* __restrict__ c_ws,         // fp32 [65536] (ws)
    float* __restrict__ out,          // fp32 (outputs | ht | ct)
    int t)
{
    __shared__ __align__(16) float Af[8][2048];   // A-rows: [x(0:1024) | h(1024:2048)]
    __shared__ float zx[8][128];                  // z exchange: [row][gate*32+u]

    const int tid = threadIdx.x;
    const int rg  = blockIdx.x >> 5;          // 0..7
    const int ugg = blockIdx.x & 31;          // 0..31
    const int rowbase = rg * 8;
    const int s    = tid & 127;               // col slot
    const int rh   = tid >> 7;                // 0..1 (row half)
    const int gate = s >> 5;                  // 0..3
    const int u    = s & 31;                  // unit within group
    const int col  = gate * 1024 + ugg * 32 + u;   // z column [0,4096)

    // ---- stage A (8 rows x 2048) fp32 into LDS, coalesced float4 ----
    const float* hsrc = out + (size_t)(t - 1) * 65536;   // h_{t-1} (exact fp32)
    #pragma unroll
    for (int i = 0; i < 16; ++i) {
        int idx = i * 256 + tid;              // float4 index in [0,4096)
        int e4  = idx * 4;
        int row = e4 >> 11;                   // 0..7
        int kk  = e4 & 2047;
        floatx4 v;
        if (kk < 1024) {
            v = *(const floatx4*)(x + (size_t)t * 65536
                                    + (size_t)(rowbase + row) * 1024 + kk);
        } else if (t > 0) {
            v = *(const floatx4*)(hsrc + (size_t)(rowbase + row) * 1024 + (kk - 1024));
        } else {
            v = (floatx4){0.f, 0.f, 0.f, 0.f};   // h0 = 0
        }
        *(floatx4*)&Af[row][kk] = v;
    }
    __syncthreads();

    // ---- 4 rows x 1 col fp32 dot over K=2048 ----
    const float* Wp = W + col;                // stride 4096 per k
    const float* Rp = R + col;
    const int r0 = rh * 4;
    float acc0 = 0.f, acc1 = 0.f, acc2 = 0.f, acc3 = 0.f;

    for (int k = 0; k < 1024; k += 4) {
        float w0 = Wp[(size_t)(k + 0) * 4096];
        float w1 = Wp[(size_t)(k + 1) * 4096];
        float w2 = Wp[(size_t)(k + 2) * 4096];
        float w3 = Wp[(size_t)(k + 3) * 4096];
        floatx4 a0 = *(const floatx4*)&Af[r0 + 0][k];
        floatx4 a1 = *(const floatx4*)&Af[r0 + 1][k];
        floatx4 a2 = *(const floatx4*)&Af[r0 + 2][k];
        floatx4 a3 = *(const floatx4*)&Af[r0 + 3][k];
        acc0 = fmaf(a0[0], w0, acc0); acc0 = fmaf(a0[1], w1, acc0);
        acc0 = fmaf(a0[2], w2, acc0); acc0 = fmaf(a0[3], w3, acc0);
        acc1 = fmaf(a1[0], w0, acc1); acc1 = fmaf(a1[1], w1, acc1);
        acc1 = fmaf(a1[2], w2, acc1); acc1 = fmaf(a1[3], w3, acc1);
        acc2 = fmaf(a2[0], w0, acc2); acc2 = fmaf(a2[1], w1, acc2);
        acc2 = fmaf(a2[2], w2, acc2); acc2 = fmaf(a2[3], w3, acc2);
        acc3 = fmaf(a3[0], w0, acc3); acc3 = fmaf(a3[1], w1, acc3);
        acc3 = fmaf(a3[2], w2, acc3); acc3 = fmaf(a3[3], w3, acc3);
    }
    for (int k = 0; k < 1024; k += 4) {
        float w0 = Rp[(size_t)(k + 0) * 4096];
        float w1 = Rp[(size_t)(k + 1) * 4096];
        float w2 = Rp[(size_t)(k + 2) * 4096];
        float w3 = Rp[(size_t)(k + 3) * 4096];
        floatx4 a0 = *(const floatx4*)&Af[r0 + 0][1024 + k];
        floatx4 a1 = *(const floatx4*)&Af[r0 + 1][1024 + k];
        floatx4 a2 = *(const floatx4*)&Af[r0 + 2][1024 + k];
        floatx4 a3 = *(const floatx4*)&Af[r0 + 3][1024 + k];
        acc0 = fmaf(a0[0], w0, acc0); acc0 = fmaf(a0[1], w1, acc0);
        acc0 = fmaf(a0[2], w2, acc0); acc0 = fmaf(a0[3], w3, acc0);
        acc1 = fmaf(a1[0], w0, acc1); acc1 = fmaf(a1[1], w1, acc1);
        acc1 = fmaf(a1[2], w2, acc1); acc1 = fmaf(a1[3], w3, acc1);
        acc2 = fmaf(a2[0], w0, acc2); acc2 = fmaf(a2[1], w1, acc2);
        acc2 = fmaf(a2[2], w2, acc2); acc2 = fmaf(a2[3], w3, acc2);
        acc3 = fmaf(a3[0], w0, acc3); acc3 = fmaf(a3[1], w1, acc3);
        acc3 = fmaf(a3[2], w2, acc3); acc3 = fmaf(a3[3], w3, acc3);
    }

    const float b = bias[col];
    zx[r0 + 0][s] = acc0 + b;
    zx[r0 + 1][s] = acc1 + b;
    zx[r0 + 2][s] = acc2 + b;
    zx[r0 + 3][s] = acc3 + b;
    __syncthreads();

    // ---- gates: thread <-> (row rr, unit uu); reads 4 gates from zx ----
    const int rr = tid >> 5;                  // 0..7
    const int uu = tid & 31;                  // 0..31
    float zi = zx[rr][ 0 + uu];
    float zf = zx[rr][32 + uu];
    float zc = zx[rr][64 + uu];
    float zo = zx[rr][96 + uu];

    const int grow = rowbase + rr;
    const int gcol = ugg * 32 + uu;
    const size_t cidx = (size_t)grow * 1024 + gcol;

    float ig = 1.0f / (1.0f + expf(-zi));
    float fg = 1.0f / (1.0f + expf(-zf));
    float og = 1.0f / (1.0f + expf(-zo));
    float cc = tanhf(zc);
    float cprev = (t == 0) ? 0.f : c_ws[cidx];
    float cn = fg * cprev + ig * cc;
    c_ws[cidx] = cn;
    float hval = og * tanhf(cn);

    out[(size_t)t * 65536 + cidx] = hval;
    if (t == T_STEPS - 1) {
        out[OUT_HT_OFF + cidx] = hval;
        out[OUT_CT_OFF + cidx] = cn;
    }
}

extern "C" void kernel_launch(void* const* d_in, const int* in_sizes, int n_in,
                              void* d_out, int out_size, void* d_ws, size_t ws_size,
                              hipStream_t stream) {
    const float* inputs = (const float*)d_in[0];
    const float* W      = (const float*)d_in[1];
    const float* R      = (const float*)d_in[2];
    const float* bias   = (const float*)d_in[3];
    float* out = (float*)d_out;

    if (ws_size < WS_NEED) {
        ws_sentinel<<<1, 64, 0, stream>>>(out);
        return;
    }
    float* c_ws = (float*)d_ws;

    for (int t = 0; t < T_STEPS; ++t) {
        lstm_step<<<256, 256, 0, stream>>>(W, R, bias, inputs, c_ws, out, t);
    }
}

// Round 9
// 23764.108 us; speedup vs baseline: 1.4630x; 1.4630x over previous
//
#include <hip/hip_runtime.h>

typedef __attribute__((ext_vector_type(8))) short short8;
typedef __attribute__((ext_vector_type(4))) float floatx4;

#define T_STEPS 512
// d_out is FP32: outputs[512][64][1024], ht[64][1024], ct[64][1024]
#define OUT_HT_OFF 33554432ull
#define OUT_CT_OFF 33619968ull

// ws: wxh bf16 [4096][1024] (8 MiB) | wxl bf16 [4096][1024] (8 MiB) | barrier
#define WXH_OFF  0ull
#define WXL_OFF  (8ull << 20)
#define BAR_OFF  (16ull << 20)
#define WS_NEED  ((16ull << 20) + 4096)

static __device__ __forceinline__ unsigned short bf16_rne(float f) {
    union { float f; unsigned int u; } v; v.f = f;
    return (unsigned short)((v.u + 0x7FFFu + ((v.u >> 16) & 1u)) >> 16);
}
static __device__ __forceinline__ float bf16f(unsigned short u) {
    union { unsigned int u; float f; } v; v.u = ((unsigned int)u) << 16;
    return v.f;
}

// tripwire: ws too small -> distinguishable sentinel (fp32 2.0 in out[0..63])
__global__ void ws_sentinel(float* out) { out[threadIdx.x] = 2.0f; }

// one-time: W fp32 [1024][4096] -> k-major bf16 hi/lo split [4096][1024]
__global__ void __launch_bounds__(256) wsplit(const float* __restrict__ W,
                                              unsigned short* __restrict__ wxh,
                                              unsigned short* __restrict__ wxl) {
    __shared__ float tile[64][65];
    const int tx = threadIdx.x & 63;
    const int ty = threadIdx.x >> 6;
    const int cb = blockIdx.x * 64;   // col tile base (0..4095)
    const int kb = blockIdx.y * 64;   // k tile base (0..1023)
    #pragma unroll
    for (int i = 0; i < 16; ++i) {
        int kl = i * 4 + ty;
        tile[kl][tx] = W[(size_t)(kb + kl) * 4096 + cb + tx];
    }
    __syncthreads();
    #pragma unroll
    for (int i = 0; i < 16; ++i) {
        int cl = i * 4 + ty;
        float v = tile[tx][cl];
        unsigned short hi = bf16_rne(v);
        unsigned short lo = bf16_rne(v - bf16f(hi));
        wxh[(size_t)(cb + cl) * 1024 + kb + tx] = hi;
        wxl[(size_t)(cb + cl) * 1024 + kb + tx] = lo;
    }
}

static __device__ __forceinline__ void gridbar(unsigned* cnt, unsigned* gen) {
    __syncthreads();
    if (threadIdx.x == 0) {
        __threadfence();  // release
        unsigned g = __hip_atomic_load(gen, __ATOMIC_RELAXED, __HIP_MEMORY_SCOPE_AGENT);
        unsigned p = __hip_atomic_fetch_add(cnt, 1u, __ATOMIC_ACQ_REL, __HIP_MEMORY_SCOPE_AGENT);
        if (p == 255u) {
            __hip_atomic_store(cnt, 0u, __ATOMIC_RELAXED, __HIP_MEMORY_SCOPE_AGENT);
            __hip_atomic_store(gen, g + 1u, __ATOMIC_RELEASE, __HIP_MEMORY_SCOPE_AGENT);
        } else {
            while (__hip_atomic_load(gen, __ATOMIC_ACQUIRE, __HIP_MEMORY_SCOPE_AGENT) == g) {
                __builtin_amdgcn_s_sleep(4);
            }
        }
        __threadfence();  // acquire
    }
    __syncthreads();
}

// persistent LSTM scan: 256 WGs (1/CU via 128KiB LDS), 256 thr (4 waves).
// WG (rg,jg): rows rg*16..+16, units jg*16..+16 (all 4 gates). Wave w lane l:
// z-col mycol = gate*1024 + jg*16 + w*4 + jj (gate=(l&15)>>2, jj=l&3).
// 2-term bf16 split everywhere (4-term MFMA products) == fp32-grade (r6==r7).
// h feedback fp32 via out[t-1]; c fp32 in VGPRs; precise expf/tanhf gates.
__global__ void __launch_bounds__(256, 1) lstm_scan(
    const float* __restrict__ R,              // [1024][4096] fp32 (resident split)
    const float* __restrict__ bias,           // [4096] fp32
    const float* __restrict__ x,              // [512][64][1024] fp32
    const unsigned short* __restrict__ wxh,   // bf16 [4096][1024] k-major
    const unsigned short* __restrict__ wxl,   // bf16 [4096][1024] k-major
    unsigned* __restrict__ bar,               // {cnt, gen}
    float* __restrict__ out)                  // fp32 (outputs | ht | ct)
{
    __shared__ __align__(16) char AxH[32768];  // x hi: 32 chunks x 1KB
    __shared__ __align__(16) char AxL[32768];  // x lo
    __shared__ __align__(16) char AhH[32768];  // h hi
    __shared__ __align__(16) char AhL[32768];  // h lo
    float* z_lds = (float*)AxH;                // 4KB reuse after MFMA phase

    const int tid  = threadIdx.x;
    const int lane = tid & 63;
    const int wave = tid >> 6;
    const int wg   = blockIdx.x;
    const int rg   = wg >> 6;
    const int jg   = wg & 63;
    const int rowbase = rg * 16;
    const int c16  = lane & 15;
    const int kgrp = lane >> 4;
    const int gate = c16 >> 2;
    const int jj   = c16 & 3;
    const int mycol = gate * 1024 + jg * 16 + wave * 4 + jj;

    // ---- resident R fragments: bf16 hi/lo split, 256 VGPRs (one-time) ----
    short8 rh[32], rl[32];
    #pragma unroll
    for (int kk = 0; kk < 32; ++kk) {
        int kb = kk * 32 + kgrp * 8;
        short8 h8, l8;
        #pragma unroll
        for (int j = 0; j < 8; ++j) {
            float v = R[(size_t)(kb + j) * 4096 + mycol];
            unsigned short hh = bf16_rne(v);
            h8[j] = (short)hh;
            l8[j] = (short)bf16_rne(v - bf16f(hh));
        }
        rh[kk] = h8; rl[kk] = l8;
    }
    const float biasreg = bias[mycol];

    // elementwise identity: thread <-> (row, unit)
    const int erow  = tid >> 4;
    const int eunit = tid & 15;
    const int ew    = eunit >> 2;
    const int ejj   = eunit & 3;
    const int grow  = rowbase + erow;
    const int gcol  = jg * 16 + eunit;
    const size_t cidx = (size_t)grow * 1024 + gcol;
    float c_state = 0.f;

    const int srow = rowbase + c16;   // staging row
    const int skof = kgrp * 8;        // staging k offset in chunk

    const unsigned short* bph = wxh + (size_t)mycol * 1024 + kgrp * 8;
    const unsigned short* bpl = wxl + (size_t)mycol * 1024 + kgrp * 8;

    for (int t = 0; t < T_STEPS; ++t) {
        const float* hsrc = out + (size_t)(t - 1) * 65536;   // h_{t-1} fp32

        // ---- stage A (x and h, both fp32 -> bf16 hi/lo) ----
        #pragma unroll
        for (int q = 0; q < 16; ++q) {
            int ck = wave * 16 + q;
            int kc = ck & 31;
            const bool isx = (ck < 32);
            const float* src = isx
                ? (x + (size_t)t * 65536 + (size_t)srow * 1024 + kc * 32 + skof)
                : (hsrc + (size_t)srow * 1024 + kc * 32 + skof);
            short8 h8 = {0,0,0,0,0,0,0,0};
            short8 l8 = {0,0,0,0,0,0,0,0};
            if (isx || t > 0) {
                floatx4 f0 = *(const floatx4*)src;
                floatx4 f1 = *(const floatx4*)(src + 4);
                #pragma unroll
                for (int j = 0; j < 4; ++j) {
                    unsigned short hh0 = bf16_rne(f0[j]);
                    unsigned short hh1 = bf16_rne(f1[j]);
                    h8[j]     = (short)hh0;
                    h8[j + 4] = (short)hh1;
                    l8[j]     = (short)bf16_rne(f0[j] - bf16f(hh0));
                    l8[j + 4] = (short)bf16_rne(f1[j] - bf16f(hh1));
                }
            }
            char* dH = isx ? AxH : AhH;
            char* dL = isx ? AxL : AhL;
            *(short8*)(dH + kc * 1024 + lane * 16) = h8;
            *(short8*)(dL + kc * 1024 + lane * 16) = l8;
        }
        __syncthreads();

        // ---- K=2048, 4-term split MFMA (x: streamed W, h: resident R) ----
        floatx4 a0 = {0,0,0,0}, a1 = {0,0,0,0}, a2 = {0,0,0,0}, a3 = {0,0,0,0};
        #pragma unroll
        for (int kk = 0; kk < 32; ++kk) {
            short8 bxh = *(const short8*)(bph + kk * 32);
            short8 bxl = *(const short8*)(bpl + kk * 32);
            short8 axh = *(const short8*)(AxH + kk * 1024 + lane * 16);
            short8 axl = *(const short8*)(AxL + kk * 1024 + lane * 16);
            a0 = __builtin_amdgcn_mfma_f32_16x16x32_bf16(axh, bxh, a0, 0, 0, 0);
            a1 = __builtin_amdgcn_mfma_f32_16x16x32_bf16(axh, bxl, a1, 0, 0, 0);
            a2 = __builtin_amdgcn_mfma_f32_16x16x32_bf16(axl, bxh, a2, 0, 0, 0);
            a3 = __builtin_amdgcn_mfma_f32_16x16x32_bf16(axl, bxl, a3, 0, 0, 0);
            short8 ahh = *(const short8*)(AhH + kk * 1024 + lane * 16);
            short8 ahl = *(const short8*)(AhL + kk * 1024 + lane * 16);
            a0 = __builtin_amdgcn_mfma_f32_16x16x32_bf16(ahh, rh[kk], a0, 0, 0, 0);
            a1 = __builtin_amdgcn_mfma_f32_16x16x32_bf16(ahh, rl[kk], a1, 0, 0, 0);
            a2 = __builtin_amdgcn_mfma_f32_16x16x32_bf16(ahl, rh[kk], a2, 0, 0, 0);
            a3 = __builtin_amdgcn_mfma_f32_16x16x32_bf16(ahl, rl[kk], a3, 0, 0, 0);
        }
        __syncthreads();   // all A reads done before z_lds aliases AxH

        // ---- z exchange (C/D map: col=lane&15, row=kgrp*4+i) ----
        #pragma unroll
        for (int i = 0; i < 4; ++i) {
            float z = ((a0[i] + a1[i]) + (a2[i] + a3[i])) + biasreg;
            z_lds[wave * 256 + (kgrp * 4 + i) * 16 + c16] = z;
        }
        __syncthreads();

        // ---- elementwise (precise gates), h/c -> out fp32 ----
        float zi = z_lds[ew * 256 + erow * 16 +  0 + ejj];
        float zf = z_lds[ew * 256 + erow * 16 +  4 + ejj];
        float zc = z_lds[ew * 256 + erow * 16 +  8 + ejj];
        float zo = z_lds[ew * 256 + erow * 16 + 12 + ejj];
        float ig = 1.0f / (1.0f + expf(-zi));
        float fg = 1.0f / (1.0f + expf(-zf));
        float og = 1.0f / (1.0f + expf(-zo));
        float cc = tanhf(zc);
        float cn = fg * c_state + ig * cc;
        c_state = cn;
        float hval = og * tanhf(cn);

        out[(size_t)t * 65536 + cidx] = hval;
        if (t == T_STEPS - 1) {
            out[OUT_HT_OFF + cidx] = hval;
            out[OUT_CT_OFF + cidx] = cn;
        }

        gridbar(bar, bar + 1);
    }
}

extern "C" void kernel_launch(void* const* d_in, const int* in_sizes, int n_in,
                              void* d_out, int out_size, void* d_ws, size_t ws_size,
                              hipStream_t stream) {
    const float* inputs = (const float*)d_in[0];
    const float* W      = (const float*)d_in[1];
    const float* R      = (const float*)d_in[2];
    const float* bias   = (const float*)d_in[3];
    float* out = (float*)d_out;

    if (ws_size < WS_NEED) {
        ws_sentinel<<<1, 64, 0, stream>>>(out);
        return;
    }

    unsigned short* wxh = (unsigned short*)((char*)d_ws + WXH_OFF);
    unsigned short* wxl = (unsigned short*)((char*)d_ws + WXL_OFF);
    unsigned*       bar = (unsigned*)((char*)d_ws + BAR_OFF);

    hipMemsetAsync(bar, 0, 64, stream);                 // barrier state = 0
    wsplit<<<dim3(64, 16), 256, 0, stream>>>(W, wxh, wxl);
    lstm_scan<<<256, 256, 0, stream>>>(R, bias, inputs, wxh, wxl, bar, out);
}

// Round 10
// 15168.530 us; speedup vs baseline: 2.2920x; 1.5667x over previous
//
#include <hip/hip_runtime.h>

typedef __attribute__((ext_vector_type(8))) short short8;
typedef __attribute__((ext_vector_type(4))) float floatx4;

#define T_STEPS 512
// d_out is FP32: outputs[512][64][1024], ht[64][1024], ct[64][1024]
#define OUT_HT_OFF 33554432ull
#define OUT_CT_OFF 33619968ull

// ws: wxh bf16 [4096][1024] (8 MiB) | wxl bf16 [4096][1024] (8 MiB) | bar (4 KiB)
#define WXH_OFF  0ull
#define WXL_OFF  (8ull << 20)
#define BAR_OFF  (16ull << 20)
#define WS_NEED  ((16ull << 20) + 4096)

// bar word-offsets (monotonic counters, all zeroed per call)
//  [xcd*32]        : per-XCD arrive counters (8 lines, 128B apart)
//  [256]           : global XCD-arrival counter
//  [288]           : generation (completed steps)
//  [320 + xcd*32]  : per-XCD slot-assignment counters

static __device__ __forceinline__ unsigned short bf16_rne(float f) {
    union { float f; unsigned int u; } v; v.f = f;
    return (unsigned short)((v.u + 0x7FFFu + ((v.u >> 16) & 1u)) >> 16);
}
static __device__ __forceinline__ float bf16f(unsigned short u) {
    union { unsigned int u; float f; } v; v.u = ((unsigned int)u) << 16;
    return v.f;
}

// tripwire: ws too small -> distinguishable sentinel (fp32 2.0 in out[0..63])
__global__ void ws_sentinel(float* out) { out[threadIdx.x] = 2.0f; }

// one-time: W fp32 [1024][4096] -> k-major bf16 hi/lo split [4096][1024]
__global__ void __launch_bounds__(256) wsplit(const float* __restrict__ W,
                                              unsigned short* __restrict__ wxh,
                                              unsigned short* __restrict__ wxl) {
    __shared__ float tile[64][65];
    const int tx = threadIdx.x & 63;
    const int ty = threadIdx.x >> 6;
    const int cb = blockIdx.x * 64;   // col tile base (0..4095)
    const int kb = blockIdx.y * 64;   // k tile base (0..1023)
    #pragma unroll
    for (int i = 0; i < 16; ++i) {
        int kl = i * 4 + ty;
        tile[kl][tx] = W[(size_t)(kb + kl) * 4096 + cb + tx];
    }
    __syncthreads();
    #pragma unroll
    for (int i = 0; i < 16; ++i) {
        int cl = i * 4 + ty;
        float v = tile[tx][cl];
        unsigned short hi = bf16_rne(v);
        unsigned short lo = bf16_rne(v - bf16f(hi));
        wxh[(size_t)(cb + cl) * 1024 + kb + tx] = hi;
        wxl[(size_t)(cb + cl) * 1024 + kb + tx] = lo;
    }
}

// fence-free hierarchical grid barrier (monotonic, relaxed agent atomics).
// __syncthreads drains vmcnt(0) before s_barrier, so every thread's sc1
// h-stores are at the coherence point before lane0's arrive-add; causality
// flows through same-address atomic RMWs at L3. No L2 invalidates issued.
static __device__ __forceinline__ void gridbar(unsigned* bar, int xcd, unsigned step1) {
    __syncthreads();
    if (threadIdx.x == 0) {
        unsigned old = __hip_atomic_fetch_add(bar + xcd * 32, 1u,
                          __ATOMIC_RELAXED, __HIP_MEMORY_SCOPE_AGENT);
        if (old == step1 * 32u - 1u) {          // last WG of this XCD
            unsigned og = __hip_atomic_fetch_add(bar + 256, 1u,
                              __ATOMIC_RELAXED, __HIP_MEMORY_SCOPE_AGENT);
            if (og == step1 * 8u - 1u) {        // last XCD
                __hip_atomic_store(bar + 288, step1,
                                   __ATOMIC_RELAXED, __HIP_MEMORY_SCOPE_AGENT);
            }
        }
        while (__hip_atomic_load(bar + 288, __ATOMIC_RELAXED,
                                 __HIP_MEMORY_SCOPE_AGENT) < step1) {
            __builtin_amdgcn_s_sleep(2);
        }
    }
    __syncthreads();
}

// persistent LSTM scan: 256 WGs (1/CU via 128KiB LDS), 256 thr (4 waves).
// Work assignment is XCD-aware: (rg,jg) derived from HW_REG_XCC_ID + atomic
// slot, so each XCD owns jg in [xcd*8, xcd*8+8) -> W-split footprint 2MB/XCD
// (L2-resident; no fences ever invalidate it).
// Math identical to r9 (== r8 fp32 oracle): 2-term bf16 split operands,
// 4-term MFMA products; h feedback fp32 via sc1 loads of out[t-1]; c fp32 in
// VGPRs; precise expf/tanhf gates.
__global__ void __launch_bounds__(256, 1) lstm_scan(
    const float* __restrict__ R,              // [1024][4096] fp32 (resident split)
    const float* __restrict__ bias,           // [4096] fp32
    const float* __restrict__ x,              // [512][64][1024] fp32
    const unsigned short* __restrict__ wxh,   // bf16 [4096][1024] k-major
    const unsigned short* __restrict__ wxl,   // bf16 [4096][1024] k-major
    unsigned* __restrict__ bar,               // barrier/assign block
    float* __restrict__ out)                  // fp32 (outputs | ht | ct)
{
    __shared__ __align__(16) char AxH[32768];  // x hi: 32 chunks x 1KB
    __shared__ __align__(16) char AxL[32768];  // x lo
    __shared__ __align__(16) char AhH[32768];  // h hi
    __shared__ __align__(16) char AhL[32768];  // h lo
    __shared__ unsigned s_as[2];
    float* z_lds = (float*)AxH;                // 4KB reuse after MFMA phase

    const int tid  = threadIdx.x;
    const int lane = tid & 63;
    const int wave = tid >> 6;

    // ---- XCD-aware work assignment (mapping-independent) ----
    if (tid == 0) {
        unsigned xcc;
        asm volatile("s_getreg_b32 %0, hwreg(HW_REG_XCC_ID)" : "=s"(xcc));
        xcc &= 7u;
        unsigned slot = __hip_atomic_fetch_add(bar + 320 + xcc * 32, 1u,
                            __ATOMIC_RELAXED, __HIP_MEMORY_SCOPE_AGENT);
        s_as[0] = xcc; s_as[1] = slot;
    }
    __syncthreads();
    const int xcd  = (int)s_as[0];
    const int slot = (int)(s_as[1] & 31u);
    const int rg   = slot >> 3;               // row-group 0..3
    const int jg   = xcd * 8 + (slot & 7);    // unit-group 0..63 (XCD-local)

    const int rowbase = rg * 16;
    const int c16  = lane & 15;
    const int kgrp = lane >> 4;
    const int gate = c16 >> 2;
    const int jj   = c16 & 3;
    const int mycol = gate * 1024 + jg * 16 + wave * 4 + jj;

    // ---- resident R fragments: bf16 hi/lo split, 256 VGPRs (one-time) ----
    short8 rh[32], rl[32];
    #pragma unroll
    for (int kk = 0; kk < 32; ++kk) {
        int kb = kk * 32 + kgrp * 8;
        short8 h8, l8;
        #pragma unroll
        for (int j = 0; j < 8; ++j) {
            float v = R[(size_t)(kb + j) * 4096 + mycol];
            unsigned short hh = bf16_rne(v);
            h8[j] = (short)hh;
            l8[j] = (short)bf16_rne(v - bf16f(hh));
        }
        rh[kk] = h8; rl[kk] = l8;
    }
    const float biasreg = bias[mycol];

    // elementwise identity: thread <-> (row, unit)
    const int erow  = tid >> 4;
    const int eunit = tid & 15;
    const int ew    = eunit >> 2;
    const int ejj   = eunit & 3;
    const int grow  = rowbase + erow;
    const int gcol  = jg * 16 + eunit;
    const size_t cidx = (size_t)grow * 1024 + gcol;
    float c_state = 0.f;

    const int srow = rowbase + c16;   // staging row
    const int skof = kgrp * 8;        // staging k offset in chunk

    const unsigned short* bph = wxh + (size_t)mycol * 1024 + kgrp * 8;
    const unsigned short* bpl = wxl + (size_t)mycol * 1024 + kgrp * 8;

    for (int t = 0; t < T_STEPS; ++t) {
        const float* hsrc = out + (size_t)(t - 1) * 65536;   // h_{t-1} fp32

        // ---- stage A: waves 0-1 x (cached loads), waves 2-3 h (sc1 loads) ----
        #pragma unroll
        for (int q = 0; q < 16; ++q) {
            int ck = wave * 16 + q;
            int kc = ck & 31;
            short8 h8 = {0,0,0,0,0,0,0,0};
            short8 l8 = {0,0,0,0,0,0,0,0};
            if (ck < 32) {
                const float* src = x + (size_t)t * 65536 + (size_t)srow * 1024 + kc * 32 + skof;
                floatx4 f0 = *(const floatx4*)src;
                floatx4 f1 = *(const floatx4*)(src + 4);
                #pragma unroll
                for (int j = 0; j < 4; ++j) {
                    unsigned short q0 = bf16_rne(f0[j]);
                    unsigned short q1 = bf16_rne(f1[j]);
                    h8[j]     = (short)q0;
                    h8[j + 4] = (short)q1;
                    l8[j]     = (short)bf16_rne(f0[j] - bf16f(q0));
                    l8[j + 4] = (short)bf16_rne(f1[j] - bf16f(q1));
                }
                *(short8*)(AxH + kc * 1024 + lane * 16) = h8;
                *(short8*)(AxL + kc * 1024 + lane * 16) = l8;
            } else {
                if (t > 0) {
                    const unsigned long long* p = (const unsigned long long*)
                        (hsrc + (size_t)srow * 1024 + kc * 32 + skof);
                    #pragma unroll
                    for (int j2 = 0; j2 < 4; ++j2) {
                        unsigned long long u = __hip_atomic_load(p + j2,
                            __ATOMIC_RELAXED, __HIP_MEMORY_SCOPE_AGENT);
                        float f0 = __uint_as_float((unsigned)u);
                        float f1 = __uint_as_float((unsigned)(u >> 32));
                        unsigned short q0 = bf16_rne(f0);
                        unsigned short q1 = bf16_rne(f1);
                        h8[j2 * 2]     = (short)q0;
                        h8[j2 * 2 + 1] = (short)q1;
                        l8[j2 * 2]     = (short)bf16_rne(f0 - bf16f(q0));
                        l8[j2 * 2 + 1] = (short)bf16_rne(f1 - bf16f(q1));
                    }
                }
                *(short8*)(AhH + kc * 1024 + lane * 16) = h8;
                *(short8*)(AhL + kc * 1024 + lane * 16) = l8;
            }
        }
        __syncthreads();

        // ---- K=2048, 4-term split MFMA (x: L2-hot W, h: resident R) ----
        floatx4 a0 = {0,0,0,0}, a1 = {0,0,0,0}, a2 = {0,0,0,0}, a3 = {0,0,0,0};
        #pragma unroll
        for (int kk = 0; kk < 32; ++kk) {
            short8 bxh = *(const short8*)(bph + kk * 32);
            short8 bxl = *(const short8*)(bpl + kk * 32);
            short8 axh = *(const short8*)(AxH + kk * 1024 + lane * 16);
            short8 axl = *(const short8*)(AxL + kk * 1024 + lane * 16);
            a0 = __builtin_amdgcn_mfma_f32_16x16x32_bf16(axh, bxh, a0, 0, 0, 0);
            a1 = __builtin_amdgcn_mfma_f32_16x16x32_bf16(axh, bxl, a1, 0, 0, 0);
            a2 = __builtin_amdgcn_mfma_f32_16x16x32_bf16(axl, bxh, a2, 0, 0, 0);
            a3 = __builtin_amdgcn_mfma_f32_16x16x32_bf16(axl, bxl, a3, 0, 0, 0);
            short8 ahh = *(const short8*)(AhH + kk * 1024 + lane * 16);
            short8 ahl = *(const short8*)(AhL + kk * 1024 + lane * 16);
            a0 = __builtin_amdgcn_mfma_f32_16x16x32_bf16(ahh, rh[kk], a0, 0, 0, 0);
            a1 = __builtin_amdgcn_mfma_f32_16x16x32_bf16(ahh, rl[kk], a1, 0, 0, 0);
            a2 = __builtin_amdgcn_mfma_f32_16x16x32_bf16(ahl, rh[kk], a2, 0, 0, 0);
            a3 = __builtin_amdgcn_mfma_f32_16x16x32_bf16(ahl, rl[kk], a3, 0, 0, 0);
        }
        __syncthreads();   // all A reads done before z_lds aliases AxH

        // ---- z exchange (C/D map: col=lane&15, row=kgrp*4+i) ----
        #pragma unroll
        for (int i = 0; i < 4; ++i) {
            float z = ((a0[i] + a1[i]) + (a2[i] + a3[i])) + biasreg;
            z_lds[wave * 256 + (kgrp * 4 + i) * 16 + c16] = z;
        }
        __syncthreads();

        // ---- elementwise (precise gates); h -> out via sc1 store ----
        float zi = z_lds[ew * 256 + erow * 16 +  0 + ejj];
        float zf = z_lds[ew * 256 + erow * 16 +  4 + ejj];
        float zc = z_lds[ew * 256 + erow * 16 +  8 + ejj];
        float zo = z_lds[ew * 256 + erow * 16 + 12 + ejj];
        float ig = 1.0f / (1.0f + expf(-zi));
        float fg = 1.0f / (1.0f + expf(-zf));
        float og = 1.0f / (1.0f + expf(-zo));
        float cc = tanhf(zc);
        float cn = fg * c_state + ig * cc;
        c_state = cn;
        float hval = og * tanhf(cn);

        __hip_atomic_store(out + (size_t)t * 65536 + cidx, hval,
                           __ATOMIC_RELAXED, __HIP_MEMORY_SCOPE_AGENT);
        if (t == T_STEPS - 1) {
            out[OUT_HT_OFF + cidx] = hval;
            out[OUT_CT_OFF + cidx] = cn;
        }

        gridbar(bar, xcd, (unsigned)(t + 1));
    }
}

extern "C" void kernel_launch(void* const* d_in, const int* in_sizes, int n_in,
                              void* d_out, int out_size, void* d_ws, size_t ws_size,
                              hipStream_t stream) {
    const float* inputs = (const float*)d_in[0];
    const float* W      = (const float*)d_in[1];
    const float* R      = (const float*)d_in[2];
    const float* bias   = (const float*)d_in[3];
    float* out = (float*)d_out;

    if (ws_size < WS_NEED) {
        ws_sentinel<<<1, 64, 0, stream>>>(out);
        return;
    }

    unsigned short* wxh = (unsigned short*)((char*)d_ws + WXH_OFF);
    unsigned short* wxl = (unsigned short*)((char*)d_ws + WXL_OFF);
    unsigned*       bar = (unsigned*)((char*)d_ws + BAR_OFF);

    hipMemsetAsync(bar, 0, 4096, stream);               // all counters = 0
    wsplit<<<dim3(64, 16), 256, 0, stream>>>(W, wxh, wxl);
    lstm_scan<<<256, 256, 0, stream>>>(R, bias, inputs, wxh, wxl, bar, out);
}

// Round 11
// 9343.999 us; speedup vs baseline: 3.7207x; 1.6233x over previous
//
#include <hip/hip_runtime.h>

typedef __attribute__((ext_vector_type(8))) short short8;
typedef __attribute__((ext_vector_type(4))) float floatx4;

#define T_STEPS 512
// d_out is FP32: outputs[512][64][1024], ht[64][1024], ct[64][1024]
#define OUT_HT_OFF 33554432ull
#define OUT_CT_OFF 33619968ull

// ws: wxh bf16 [4096][1024] (8 MiB) | wxl bf16 [4096][1024] (8 MiB) | bar (4 KiB)
#define WXH_OFF  0ull
#define WXL_OFF  (8ull << 20)
#define BAR_OFF  (16ull << 20)
#define WS_NEED  ((16ull << 20) + 4096)

// bar word-offsets (monotonic counters, zeroed per call):
//  [xcd*32] per-XCD arrive | [256] XCD-arrival | [288] generation | [320+xcd*32] slots

static __device__ __forceinline__ unsigned short bf16_rne(float f) {
    union { float f; unsigned int u; } v; v.f = f;
    return (unsigned short)((v.u + 0x7FFFu + ((v.u >> 16) & 1u)) >> 16);
}
static __device__ __forceinline__ float bf16f(unsigned short u) {
    union { unsigned int u; float f; } v; v.u = ((unsigned int)u) << 16;
    return v.f;
}

__global__ void ws_sentinel(float* out) { out[threadIdx.x] = 2.0f; }

// one-time: W fp32 [1024][4096] -> k-major bf16 hi/lo split [4096][1024]
__global__ void __launch_bounds__(256) wsplit(const float* __restrict__ W,
                                              unsigned short* __restrict__ wxh,
                                              unsigned short* __restrict__ wxl) {
    __shared__ float tile[64][65];
    const int tx = threadIdx.x & 63;
    const int ty = threadIdx.x >> 6;
    const int cb = blockIdx.x * 64;
    const int kb = blockIdx.y * 64;
    #pragma unroll
    for (int i = 0; i < 16; ++i) {
        int kl = i * 4 + ty;
        tile[kl][tx] = W[(size_t)(kb + kl) * 4096 + cb + tx];
    }
    __syncthreads();
    #pragma unroll
    for (int i = 0; i < 16; ++i) {
        int cl = i * 4 + ty;
        float v = tile[tx][cl];
        unsigned short hi = bf16_rne(v);
        unsigned short lo = bf16_rne(v - bf16f(hi));
        wxh[(size_t)(cb + cl) * 1024 + kb + tx] = hi;
        wxl[(size_t)(cb + cl) * 1024 + kb + tx] = lo;
    }
}

// fence-free hierarchical barrier, split into arrive / wait so the xW
// precompute for step t+1 runs inside the wait window.
static __device__ __forceinline__ void bar_arrive(unsigned* bar, int xcd, unsigned s) {
    unsigned old = __hip_atomic_fetch_add(bar + xcd * 32, 1u,
                      __ATOMIC_RELAXED, __HIP_MEMORY_SCOPE_AGENT);
    if (old == s * 32u - 1u) {
        unsigned og = __hip_atomic_fetch_add(bar + 256, 1u,
                          __ATOMIC_RELAXED, __HIP_MEMORY_SCOPE_AGENT);
        if (og == s * 8u - 1u) {
            __hip_atomic_store(bar + 288, s,
                               __ATOMIC_RELAXED, __HIP_MEMORY_SCOPE_AGENT);
        }
    }
}
static __device__ __forceinline__ void bar_wait(unsigned* bar, unsigned s) {
    while (__hip_atomic_load(bar + 288, __ATOMIC_RELAXED,
                             __HIP_MEMORY_SCOPE_AGENT) < s) {
        __builtin_amdgcn_s_sleep(2);
    }
}

// persistent LSTM scan, software-pipelined:
//   critical path per step: barrier -> stage h -> h.R MFMA (R VGPR-resident,
//   acc seeded with precomputed zx[t]) -> gates -> store h -> arrive.
//   zx[t+1] = x[t+1].W + b is computed AFTER arrive, inside the wait window
//   (W streams from L2; its latency is off the critical path). x[t+1] is
//   register-prefetched at step start to hide HBM latency.
__global__ void __launch_bounds__(256, 1) lstm_scan(
    const float* __restrict__ R,              // [1024][4096] fp32 (resident split)
    const float* __restrict__ bias,           // [4096] fp32
    const float* __restrict__ x,              // [512][64][1024] fp32
    const unsigned short* __restrict__ wxh,   // bf16 [4096][1024] k-major
    const unsigned short* __restrict__ wxl,   // bf16 [4096][1024] k-major
    unsigned* __restrict__ bar,
    float* __restrict__ out)                  // fp32 (outputs | ht | ct)
{
    __shared__ __align__(16) char AxH[32768];  // x[t+1] hi: 32 chunks x 1KB
    __shared__ __align__(16) char AxL[32768];  // x[t+1] lo
    __shared__ __align__(16) char AhH[32768];  // h[t-1] hi
    __shared__ __align__(16) char AhL[32768];  // h[t-1] lo
    __shared__ float zxl[1024];                // z exchange (4KB)
    __shared__ unsigned s_as[2];

    const int tid  = threadIdx.x;
    const int lane = tid & 63;
    const int wave = tid >> 6;

    // ---- XCD-aware work assignment ----
    if (tid == 0) {
        unsigned xcc;
        asm volatile("s_getreg_b32 %0, hwreg(HW_REG_XCC_ID)" : "=s"(xcc));
        xcc &= 7u;
        unsigned slot = __hip_atomic_fetch_add(bar + 320 + xcc * 32, 1u,
                            __ATOMIC_RELAXED, __HIP_MEMORY_SCOPE_AGENT);
        s_as[0] = xcc; s_as[1] = slot;
    }
    __syncthreads();
    const int xcd  = (int)s_as[0];
    const int slot = (int)(s_as[1] & 31u);
    const int rg   = slot >> 3;               // row-group 0..3
    const int jg   = xcd * 8 + (slot & 7);    // unit-group (XCD-local W cols)

    const int rowbase = rg * 16;
    const int c16  = lane & 15;
    const int kgrp = lane >> 4;
    const int gate = c16 >> 2;
    const int jj   = c16 & 3;
    const int mycol = gate * 1024 + jg * 16 + wave * 4 + jj;

    // ---- resident R fragments: bf16 hi/lo split (256 VGPR) ----
    short8 rh[32], rl[32];
    #pragma unroll
    for (int kk = 0; kk < 32; ++kk) {
        int kb = kk * 32 + kgrp * 8;
        short8 h8, l8;
        #pragma unroll
        for (int j = 0; j < 8; ++j) {
            float v = R[(size_t)(kb + j) * 4096 + mycol];
            unsigned short hh = bf16_rne(v);
            h8[j] = (short)hh;
            l8[j] = (short)bf16_rne(v - bf16f(hh));
        }
        rh[kk] = h8; rl[kk] = l8;
    }
    const float biasreg = bias[mycol];

    const int erow  = tid >> 4;
    const int eunit = tid & 15;
    const int ew    = eunit >> 2;
    const int ejj   = eunit & 3;
    const int grow  = rowbase + erow;
    const int gcol  = jg * 16 + eunit;
    const size_t cidx = (size_t)grow * 1024 + gcol;
    float c_state = 0.f;

    const int srow = rowbase + c16;
    const int skof = kgrp * 8;

    const unsigned short* bph = wxh + (size_t)mycol * 1024 + kgrp * 8;
    const unsigned short* bpl = wxl + (size_t)mycol * 1024 + kgrp * 8;

    // ---- prologue: stage x[0], compute zx[0] ----
    floatx4 zxcur;
    {
        #pragma unroll
        for (int q = 0; q < 8; ++q) {
            int kc = wave * 8 + q;
            const float* src = x + (size_t)srow * 1024 + kc * 32 + skof;
            floatx4 f0 = *(const floatx4*)src;
            floatx4 f1 = *(const floatx4*)(src + 4);
            short8 h8, l8;
            #pragma unroll
            for (int j = 0; j < 4; ++j) {
                unsigned short q0 = bf16_rne(f0[j]);
                unsigned short q1 = bf16_rne(f1[j]);
                h8[j] = (short)q0; h8[j + 4] = (short)q1;
                l8[j] = (short)bf16_rne(f0[j] - bf16f(q0));
                l8[j + 4] = (short)bf16_rne(f1[j] - bf16f(q1));
            }
            *(short8*)(AxH + kc * 1024 + lane * 16) = h8;
            *(short8*)(AxL + kc * 1024 + lane * 16) = l8;
        }
        __syncthreads();
        floatx4 b0 = {0,0,0,0}, b1 = {0,0,0,0}, b2 = {0,0,0,0}, b3 = {0,0,0,0};
        #pragma unroll
        for (int kk = 0; kk < 32; ++kk) {
            short8 bxh = *(const short8*)(bph + kk * 32);
            short8 bxl = *(const short8*)(bpl + kk * 32);
            short8 axh = *(const short8*)(AxH + kk * 1024 + lane * 16);
            short8 axl = *(const short8*)(AxL + kk * 1024 + lane * 16);
            b0 = __builtin_amdgcn_mfma_f32_16x16x32_bf16(axh, bxh, b0, 0, 0, 0);
            b1 = __builtin_amdgcn_mfma_f32_16x16x32_bf16(axh, bxl, b1, 0, 0, 0);
            b2 = __builtin_amdgcn_mfma_f32_16x16x32_bf16(axl, bxh, b2, 0, 0, 0);
            b3 = __builtin_amdgcn_mfma_f32_16x16x32_bf16(axl, bxl, b3, 0, 0, 0);
        }
        #pragma unroll
        for (int i = 0; i < 4; ++i)
            zxcur[i] = ((b0[i] + b1[i]) + (b2[i] + b3[i])) + biasreg;
    }

    for (int t = 0; t < T_STEPS; ++t) {
        const bool more = (t + 1 < T_STEPS);
        const float* hsrc = out + (size_t)(t - 1) * 65536;

        // ---- (a) prefetch x[t+1] into regs; stage h_{t-1} -> LDS ----
        floatx4 xp0[8], xp1[8];
        if (more) {
            #pragma unroll
            for (int q = 0; q < 8; ++q) {
                int kc = wave * 8 + q;
                const float* src = x + (size_t)(t + 1) * 65536
                                     + (size_t)srow * 1024 + kc * 32 + skof;
                xp0[q] = *(const floatx4*)src;
                xp1[q] = *(const floatx4*)(src + 4);
            }
        }
        #pragma unroll
        for (int q = 0; q < 8; ++q) {
            int kc = wave * 8 + q;
            short8 h8 = {0,0,0,0,0,0,0,0};
            short8 l8 = {0,0,0,0,0,0,0,0};
            if (t > 0) {
                const unsigned long long* p = (const unsigned long long*)
                    (hsrc + (size_t)srow * 1024 + kc * 32 + skof);
                #pragma unroll
                for (int j2 = 0; j2 < 4; ++j2) {
                    unsigned long long u = __hip_atomic_load(p + j2,
                        __ATOMIC_RELAXED, __HIP_MEMORY_SCOPE_AGENT);
                    float f0 = __uint_as_float((unsigned)u);
                    float f1 = __uint_as_float((unsigned)(u >> 32));
                    unsigned short q0 = bf16_rne(f0);
                    unsigned short q1 = bf16_rne(f1);
                    h8[j2 * 2]     = (short)q0;
                    h8[j2 * 2 + 1] = (short)q1;
                    l8[j2 * 2]     = (short)bf16_rne(f0 - bf16f(q0));
                    l8[j2 * 2 + 1] = (short)bf16_rne(f1 - bf16f(q1));
                }
            }
            *(short8*)(AhH + kc * 1024 + lane * 16) = h8;
            *(short8*)(AhL + kc * 1024 + lane * 16) = l8;
        }
        __syncthreads();                                   // (b)

        // ---- (c) h.R MFMA, acc seeded with zx[t] (R resident: no mem) ----
        floatx4 a0 = zxcur;
        floatx4 a1 = {0,0,0,0}, a2 = {0,0,0,0}, a3 = {0,0,0,0};
        #pragma unroll
        for (int kk = 0; kk < 32; ++kk) {
            short8 ahh = *(const short8*)(AhH + kk * 1024 + lane * 16);
            short8 ahl = *(const short8*)(AhL + kk * 1024 + lane * 16);
            a0 = __builtin_amdgcn_mfma_f32_16x16x32_bf16(ahh, rh[kk], a0, 0, 0, 0);
            a1 = __builtin_amdgcn_mfma_f32_16x16x32_bf16(ahh, rl[kk], a1, 0, 0, 0);
            a2 = __builtin_amdgcn_mfma_f32_16x16x32_bf16(ahl, rh[kk], a2, 0, 0, 0);
            a3 = __builtin_amdgcn_mfma_f32_16x16x32_bf16(ahl, rl[kk], a3, 0, 0, 0);
        }

        // ---- (d) z exchange + gates + state + h store ----
        #pragma unroll
        for (int i = 0; i < 4; ++i) {
            float z = (a0[i] + a1[i]) + (a2[i] + a3[i]);   // bias in zxcur
            zxl[wave * 256 + (kgrp * 4 + i) * 16 + c16] = z;
        }
        __syncthreads();
        {
            float zi = zxl[ew * 256 + erow * 16 +  0 + ejj];
            float zf = zxl[ew * 256 + erow * 16 +  4 + ejj];
            float zc = zxl[ew * 256 + erow * 16 +  8 + ejj];
            float zo = zxl[ew * 256 + erow * 16 + 12 + ejj];
            float ig = 1.0f / (1.0f + expf(-zi));
            float fg = 1.0f / (1.0f + expf(-zf));
            float og = 1.0f / (1.0f + expf(-zo));
            float cc = tanhf(zc);
            float cn = fg * c_state + ig * cc;
            c_state = cn;
            float hval = og * tanhf(cn);
            __hip_atomic_store(out + (size_t)t * 65536 + cidx, hval,
                               __ATOMIC_RELAXED, __HIP_MEMORY_SCOPE_AGENT);
            if (t == T_STEPS - 1) {
                out[OUT_HT_OFF + cidx] = hval;
                out[OUT_CT_OFF + cidx] = cn;
            }
        }

        if (more) {
            // ---- (e) stage x[t+1] (prefetched regs) -> LDS ----
            #pragma unroll
            for (int q = 0; q < 8; ++q) {
                int kc = wave * 8 + q;
                short8 h8, l8;
                #pragma unroll
                for (int j = 0; j < 4; ++j) {
                    unsigned short q0 = bf16_rne(xp0[q][j]);
                    unsigned short q1 = bf16_rne(xp1[q][j]);
                    h8[j] = (short)q0; h8[j + 4] = (short)q1;
                    l8[j] = (short)bf16_rne(xp0[q][j] - bf16f(q0));
                    l8[j + 4] = (short)bf16_rne(xp1[q][j] - bf16f(q1));
                }
                *(short8*)(AxH + kc * 1024 + lane * 16) = h8;
                *(short8*)(AxL + kc * 1024 + lane * 16) = l8;
            }
            __syncthreads();                               // (f) h stores drained
            if (tid == 0) bar_arrive(bar, xcd, (unsigned)(t + 1));   // (g)

            // ---- (h) zx[t+1] = x[t+1].W + b  (inside barrier window) ----
            floatx4 b0 = {0,0,0,0}, b1 = {0,0,0,0}, b2 = {0,0,0,0}, b3 = {0,0,0,0};
            #pragma unroll
            for (int kk = 0; kk < 32; ++kk) {
                short8 bxh = *(const short8*)(bph + kk * 32);
                short8 bxl = *(const short8*)(bpl + kk * 32);
                short8 axh = *(const short8*)(AxH + kk * 1024 + lane * 16);
                short8 axl = *(const short8*)(AxL + kk * 1024 + lane * 16);
                b0 = __builtin_amdgcn_mfma_f32_16x16x32_bf16(axh, bxh, b0, 0, 0, 0);
                b1 = __builtin_amdgcn_mfma_f32_16x16x32_bf16(axh, bxl, b1, 0, 0, 0);
                b2 = __builtin_amdgcn_mfma_f32_16x16x32_bf16(axl, bxh, b2, 0, 0, 0);
                b3 = __builtin_amdgcn_mfma_f32_16x16x32_bf16(axl, bxl, b3, 0, 0, 0);
            }
            #pragma unroll
            for (int i = 0; i < 4; ++i)
                zxcur[i] = ((b0[i] + b1[i]) + (b2[i] + b3[i])) + biasreg;

            // ---- (i) wait for all h_t stores ----
            if (tid == 0) bar_wait(bar, (unsigned)(t + 1));
            __syncthreads();
        }
    }
}

extern "C" void kernel_launch(void* const* d_in, const int* in_sizes, int n_in,
                              void* d_out, int out_size, void* d_ws, size_t ws_size,
                              hipStream_t stream) {
    const float* inputs = (const float*)d_in[0];
    const float* W      = (const float*)d_in[1];
    const float* R      = (const float*)d_in[2];
    const float* bias   = (const float*)d_in[3];
    float* out = (float*)d_out;

    if (ws_size < WS_NEED) {
        ws_sentinel<<<1, 64, 0, stream>>>(out);
        return;
    }

    unsigned short* wxh = (unsigned short*)((char*)d_ws + WXH_OFF);
    unsigned short* wxl = (unsigned short*)((char*)d_ws + WXL_OFF);
    unsigned*       bar = (unsigned*)((char*)d_ws + BAR_OFF);

    hipMemsetAsync(bar, 0, 4096, stream);
    wsplit<<<dim3(64, 16), 256, 0, stream>>>(W, wxh, wxl);
    lstm_scan<<<256, 256, 0, stream>>>(R, bias, inputs, wxh, wxl, bar, out);
}